// Round 5
// baseline (892.373 us; speedup 1.0000x reference)
//
#include <hip/hip_runtime.h>
#include <float.h>

// ---------------------------------------------------------------------------
// MPNN forward.  msg@w1 decomposed: per-node p=h@w1a, q=h@w1b (fused gemm_pq,
// f16 output), per-edge ea@w1c fp32 VALU; edge GEMM t1@w2 via f16 MFMA;
// CSR-grouped blocks (6 nodes), LDS segmented max, BN stats fused.
//
// ws budget: hard bound proven R2/R3: ws_size in [38,601,024, 38,617,408).
// Current use: hagg f32 (12.8M) | pq f16 (12.8M) | ends (200K) = 25.8 MB.
// perm/w2h/stats live in d_out (rebuilt每call; head GEMMs overwrite last).
// ---------------------------------------------------------------------------

typedef _Float16 half8 __attribute__((ext_vector_type(8)));
typedef _Float16 half4 __attribute__((ext_vector_type(4)));
typedef float floatx4 __attribute__((ext_vector_type(4)));

__device__ __forceinline__ unsigned enc(float f) {
    unsigned u = __float_as_uint(f);
    return (u & 0x80000000u) ? ~u : (u | 0x80000000u);
}
__device__ __forceinline__ float dec(unsigned u) {
    return (u & 0x80000000u) ? __uint_as_float(u & 0x7fffffffu)
                             : __uint_as_float(~u);
}

// ---------------------------------------------------------------------------
// Generic small GEMM: C[M][N] = op(A[M][64] @ W[64][N] + bias), K fixed = 64.
// ---------------------------------------------------------------------------
template<int N, int M_TILE, bool RELU, bool BIAS>
__global__ __launch_bounds__(256) void gemm_k64(
    const float* __restrict__ A, const float* __restrict__ W,
    const float* __restrict__ bias, float* __restrict__ C, int M)
{
    constexpr int K = 64;
    constexpr int TCOLS = N / 4;
    constexpr int TROWS = 256 / TCOLS;
    constexpr int RPT = M_TILE / TROWS;
    __shared__ __align__(16) float Ws[K * N];
    __shared__ __align__(16) float As[M_TILE * (K + 4)];

    const int t = threadIdx.x;
    const int m0 = blockIdx.x * M_TILE;

    for (int i = t; i < K * N; i += 256) Ws[i] = W[i];

    for (int rr = 0; rr < M_TILE; rr += 16) {
        int r = rr + (t >> 4);
        int c4 = (t & 15) * 4;
        int row = m0 + r;
        float4 v = make_float4(0.f, 0.f, 0.f, 0.f);
        if (row < M) v = *(const float4*)&A[(size_t)row * K + c4];
        *(float4*)&As[r * (K + 4) + c4] = v;
    }
    __syncthreads();

    const int tc = t % TCOLS;
    const int tr = t / TCOLS;
    float4 acc[RPT];
    float4 bv = make_float4(0.f, 0.f, 0.f, 0.f);
    if (BIAS) {
        bv.x = bias[tc * 4 + 0]; bv.y = bias[tc * 4 + 1];
        bv.z = bias[tc * 4 + 2]; bv.w = bias[tc * 4 + 3];
    }
#pragma unroll
    for (int i = 0; i < RPT; ++i) acc[i] = bv;

#pragma unroll 8
    for (int k = 0; k < K; ++k) {
        float4 w = *(const float4*)&Ws[k * N + tc * 4];
#pragma unroll
        for (int i = 0; i < RPT; ++i) {
            float a = As[(tr + i * TROWS) * (K + 4) + k];
            acc[i].x = fmaf(a, w.x, acc[i].x);
            acc[i].y = fmaf(a, w.y, acc[i].y);
            acc[i].z = fmaf(a, w.z, acc[i].z);
            acc[i].w = fmaf(a, w.w, acc[i].w);
        }
    }
#pragma unroll
    for (int i = 0; i < RPT; ++i) {
        int row = m0 + tr + i * TROWS;
        if (row < M) {
            float4 o = acc[i];
            if (RELU) {
                o.x = fmaxf(o.x, 0.f); o.y = fmaxf(o.y, 0.f);
                o.z = fmaxf(o.z, 0.f); o.w = fmaxf(o.w, 0.f);
            }
            *(float4*)&C[(size_t)row * N + tc * 4] = o;
        }
    }
}

// ---------------------------------------------------------------------------
// Fused p|q GEMM, f16 output: PQ[M][128] = (_Float16)(A[M][64] @ [w1a|w1b])
// ---------------------------------------------------------------------------
__global__ __launch_bounds__(256) void gemm_pq(
    const float* __restrict__ A, const float* __restrict__ W,
    _Float16* __restrict__ PQ, int M)
{
    __shared__ __align__(16) float Ws[64 * 128];
    __shared__ __align__(16) float As[64 * 68];

    const int t = threadIdx.x;
    const int m0 = blockIdx.x * 64;

    for (int i = t; i < 64 * 128; i += 256) {
        int k = i >> 7, n = i & 127;
        Ws[i] = W[(size_t)((n < 64 ? k : 64 + k)) * 64 + (n & 63)];
    }
    for (int rr = 0; rr < 64; rr += 16) {
        int r = rr + (t >> 4);
        int c4 = (t & 15) * 4;
        int row = m0 + r;
        float4 v = make_float4(0.f, 0.f, 0.f, 0.f);
        if (row < M) v = *(const float4*)&A[(size_t)row * 64 + c4];
        *(float4*)&As[r * 68 + c4] = v;
    }
    __syncthreads();

    const int tc = t & 31;
    const int tr = t >> 5;
    float4 acc[8];
#pragma unroll
    for (int i = 0; i < 8; ++i) acc[i] = make_float4(0.f, 0.f, 0.f, 0.f);

#pragma unroll 8
    for (int k = 0; k < 64; ++k) {
        float4 w = *(const float4*)&Ws[k * 128 + tc * 4];
#pragma unroll
        for (int i = 0; i < 8; ++i) {
            float a = As[(tr + i * 8) * 68 + k];
            acc[i].x = fmaf(a, w.x, acc[i].x);
            acc[i].y = fmaf(a, w.y, acc[i].y);
            acc[i].z = fmaf(a, w.z, acc[i].z);
            acc[i].w = fmaf(a, w.w, acc[i].w);
        }
    }
#pragma unroll
    for (int i = 0; i < 8; ++i) {
        int row = m0 + tr + i * 8;
        if (row < M) {
            half4 o = { (_Float16)acc[i].x, (_Float16)acc[i].y,
                        (_Float16)acc[i].z, (_Float16)acc[i].w };
            *(half4*)&PQ[(size_t)row * 128 + tc * 4] = o;
        }
    }
}

// ---------------------------------------------------------------------------
// CSR build
// ---------------------------------------------------------------------------
__global__ __launch_bounds__(256) void zero_cs(int* __restrict__ cnt,
                                               float* __restrict__ stats, int M)
{
    int i = blockIdx.x * 256 + threadIdx.x;
    if (i < M) cnt[i] = 0;
    if (blockIdx.x == 0) stats[threadIdx.x] = 0.f;   // 256 floats (2 layers)
}

__global__ __launch_bounds__(256) void hist_tgt(const int* __restrict__ tgt,
                                                int* __restrict__ cnt, int E)
{
    int e = blockIdx.x * 256 + threadIdx.x;
    if (e < E) atomicAdd(&cnt[tgt[e]], 1);
}

__global__ __launch_bounds__(1024) void scan_counts(int* __restrict__ cnt, int M)
{
    __shared__ int part[1024];
    const int t = threadIdx.x;
    const int chunk = (M + 1023) / 1024;
    const int b = t * chunk;
    const int e = min(b + chunk, M);
    int s = 0;
    for (int i = b; i < e; ++i) s += cnt[i];
    part[t] = s;
    __syncthreads();
    for (int off = 1; off < 1024; off <<= 1) {
        int add = (t >= off) ? part[t - off] : 0;
        __syncthreads();
        part[t] += add;
        __syncthreads();
    }
    int run = (t > 0) ? part[t - 1] : 0;
    for (int i = b; i < e; ++i) {
        int v = cnt[i];
        cnt[i] = run;
        run += v;
    }
}

// fill: perm[pos]=e.  After this, arr[n] == end of node n.
__global__ __launch_bounds__(256) void fill_csr(const int* __restrict__ tgt,
    int* __restrict__ arr, int* __restrict__ perm, int E)
{
    int e = blockIdx.x * 256 + threadIdx.x;
    if (e < E) {
        int pos = atomicAdd(&arr[tgt[e]], 1);
        perm[pos] = e;
    }
}

// ---------------------------------------------------------------------------
// Pack w2 (both layers) into f16 MFMA B-fragment order.
// ---------------------------------------------------------------------------
__global__ __launch_bounds__(256) void pack_w2(const float* __restrict__ w2,
                                               _Float16* __restrict__ w2h)
{
    int id = blockIdx.x * 256 + threadIdx.x;
    if (id >= 1024) return;
    int l = id >> 9, rem = id & 511;
    int frag = rem >> 6, lane = rem & 63;
    int nt = frag >> 1, kc = frag & 1;
    const float* W = w2 + (size_t)l * 4096;
    _Float16* O = w2h + (size_t)l * 4096 + (frag * 64 + lane) * 8;
    int n = nt * 16 + (lane & 15);
    int k0 = kc * 32 + (lane >> 4) * 8;
#pragma unroll
    for (int j = 0; j < 8; ++j) O[j] = (_Float16)W[(k0 + j) * 64 + n];
}

// ---------------------------------------------------------------------------
// Fused per-node edge-MLP + segmented max + BN stats.  MFMA phase 2.
//   NPB=6 nodes/block (avg 96 edges, sd~10 -> ~95% single ET=112 tile),
//   LDS ~31 KB -> 5 blocks/CU.
// ---------------------------------------------------------------------------
#define NPB 6
#define ET  112
#define TSH 72    // t1 LDS row stride in halfs (144 B -> 2-way b128, free)

__global__ __launch_bounds__(256, 5) void node_agg(
    const _Float16* __restrict__ pq, const float* __restrict__ ea,
    const int* __restrict__ srcG,
    const int* __restrict__ ends, const int* __restrict__ perm,
    const float* __restrict__ w1c, const float* __restrict__ b1,
    const _Float16* __restrict__ w2h, const float* __restrict__ b2,
    float* __restrict__ hout, float* __restrict__ stats, int M)
{
    __shared__ __align__(16) _Float16 t1h[ET * TSH];   // 15.8 KB
    __shared__ __align__(16) float eas[ET * 16];       //  7.2 KB
    __shared__ __align__(16) float w1cs[16 * 64];      //  4.0 KB
    __shared__ __align__(16) float ps[NPB * 64];       //  1.5 KB
    __shared__ __align__(16) unsigned rmu[NPB * 68];   //  1.6 KB
    __shared__ __align__(16) int sidx[ET];
    __shared__ int endsL[NPB + 1];
    __shared__ unsigned char lnodS[ET];

    const int t = threadIdx.x;
    const int lane = t & 63;
    const int wid = t >> 6;
    const int n0 = blockIdx.x * NPB;

    for (int i = t; i < 16 * 64; i += 256) w1cs[i] = w1c[i];
    if (t <= NPB) {
        int n = n0 + t - 1;
        endsL[t] = (t == 0) ? ((n0 == 0) ? 0 : ends[n0 - 1])
                            : ((n < M) ? ends[n] : ends[M - 1]);
    }
    {
        int c = t & 63;
        for (int nn = t >> 6; nn < NPB; nn += 4) {
            int node = n0 + nn;
            ps[nn * 64 + c] =
                ((node < M) ? (float)pq[(size_t)node * 128 + c] : 0.f) + b1[c];
        }
    }
    for (int i = t; i < NPB * 68; i += 256) rmu[i] = 0u;   // 0 < enc(anything)

    // B fragments (w2), same for all waves
    half8 bfrag[4][2];
#pragma unroll
    for (int nt = 0; nt < 4; ++nt)
#pragma unroll
        for (int kc = 0; kc < 2; ++kc)
            bfrag[nt][kc] = *(const half8*)(w2h + ((nt * 2 + kc) * 64 + lane) * 8);

    __syncthreads();

    const int eBeg = endsL[0], eEnd = endsL[NPB];

    for (int tile = eBeg; tile < eEnd; tile += ET) {
        const int cnt = min(ET, eEnd - tile);

        // ---- stage metadata + edge_attr (one barrier) ----
        for (int i = t; i < ET; i += 256) {
            if (i < cnt) {
                int gp = tile + i;
                sidx[i] = srcG[perm[gp]];
                int L = 0;
                while (gp >= endsL[L + 1]) ++L;
                lnodS[i] = (unsigned char)L;
            } else { sidx[i] = 0; lnodS[i] = 0; }
        }
        for (int i = t; i < ET * 16; i += 256) {
            int ei = i >> 4;
            float v = 0.f;
            if (ei < cnt) {
                int pe = perm[tile + ei];          // uniform per 16 lanes (L2 broadcast)
                v = ea[(size_t)pe * 16 + (i & 15)];
            }
            eas[i] = v;
        }
        __syncthreads();

        // ---- phase 1: t1 = relu(p[tgt]+b1 + q[src] + ea@w1c) -> f16 LDS ----
        {
            const int c = t & 63;
            for (int i = wid; i < cnt; i += 8) {
                const int i2 = i + 4;
                const bool has2 = (i2 < cnt);
                float v0 = ps[lnodS[i] * 64 + c]
                         + (float)pq[(size_t)sidx[i] * 128 + 64 + c];
                float v1 = 0.f;
                if (has2)
                    v1 = ps[lnodS[i2] * 64 + c]
                       + (float)pq[(size_t)sidx[i2] * 128 + 64 + c];
#pragma unroll
                for (int j = 0; j < 16; ++j) {
                    const float w = w1cs[j * 64 + c];
                    v0 = fmaf(eas[i * 16 + j], w, v0);
                    if (has2) v1 = fmaf(eas[i2 * 16 + j], w, v1);
                }
                t1h[i * TSH + c] = (_Float16)fmaxf(v0, 0.f);
                if (has2) t1h[i2 * TSH + c] = (_Float16)fmaxf(v1, 0.f);
            }
        }
        __syncthreads();

        // ---- phase 2: m = t1 @ w2 via MFMA, segmented max into rmu ----
        {
            const int quad = lane >> 4;
            const int col = lane & 15;
            for (int mt = wid; mt * 16 < cnt; mt += 4) {
                const int e0 = mt * 16;
                floatx4 acc[4] = {{0.f,0.f,0.f,0.f},{0.f,0.f,0.f,0.f},
                                  {0.f,0.f,0.f,0.f},{0.f,0.f,0.f,0.f}};
#pragma unroll
                for (int kc = 0; kc < 2; ++kc) {
                    half8 a = *(const half8*)&t1h[(e0 + col) * TSH + kc * 32 + quad * 8];
#pragma unroll
                    for (int nt = 0; nt < 4; ++nt)
                        acc[nt] = __builtin_amdgcn_mfma_f32_16x16x32_f16(
                            a, bfrag[nt][kc], acc[nt], 0, 0, 0);
                }
                const int r0 = e0 + quad * 4;
#pragma unroll
                for (int nt = 0; nt < 4; ++nt) {
                    int curL = -1;
                    float best = 0.f;
#pragma unroll
                    for (int r = 0; r < 4; ++r) {
                        int ge = r0 + r;
                        if (ge < cnt) {
                            int L = lnodS[ge];
                            float v = acc[nt][r];
                            if (L != curL) {
                                if (curL >= 0)
                                    atomicMax(&rmu[curL * 68 + nt * 16 + col], enc(best));
                                curL = L; best = v;
                            } else best = fmaxf(best, v);
                        }
                    }
                    if (curL >= 0)
                        atomicMax(&rmu[curL * 68 + nt * 16 + col], enc(best));
                }
            }
        }
        __syncthreads();
    }

    // ---- final store (+b2) + BN stats ----
    for (int idx = t; idx < NPB * 64; idx += 256) {
        int L = idx >> 6, c = idx & 63;
        int node = n0 + L;
        float v = 0.f;
        if (node < M) {
            if (endsL[L + 1] > endsL[L]) v = dec(rmu[L * 68 + c]) + b2[c];
            hout[(size_t)node * 64 + c] = v;
        }
        ((float*)rmu)[L * 68 + c] = v;   // own slot: no race
    }
    __syncthreads();
    if (t < 64) {
        float s = 0.f, s2 = 0.f;
#pragma unroll
        for (int L = 0; L < NPB; ++L) {
            float v = ((float*)rmu)[L * 68 + t];
            s += v;
            s2 = fmaf(v, v, s2);
        }
        atomicAdd(&stats[t], s);
        atomicAdd(&stats[64 + t], s2);
    }
}

// ---------------------------------------------------------------------------
// BN normalize + relu, in place
// ---------------------------------------------------------------------------
__global__ __launch_bounds__(256) void bn_norm(float* __restrict__ h,
    const float* __restrict__ stats, const float* __restrict__ gamma,
    const float* __restrict__ beta, int M)
{
    int idx = blockIdx.x * 256 + threadIdx.x;
    if (idx >= M * 64) return;
    int c = idx & 63;
    float inv = 1.f / (float)M;
    float mu = stats[c] * inv;
    float var = fmaxf(stats[64 + c] * inv - mu * mu, 0.f);
    float v = h[idx];
    h[idx] = fmaxf(gamma[c] * (v - mu) * rsqrtf(var + 1e-5f) + beta[c], 0.f);
}

// ---------------------------------------------------------------------------
extern "C" void kernel_launch(void* const* d_in, const int* in_sizes, int n_in,
                              void* d_out, int out_size, void* d_ws, size_t ws_size,
                              hipStream_t stream)
{
    const float* x     = (const float*)d_in[0];
    const int*   eidx  = (const int*)  d_in[1];
    const float* ea    = (const float*)d_in[2];
    const float* w_in  = (const float*)d_in[3];
    const float* b_in  = (const float*)d_in[4];
    const float* w1    = (const float*)d_in[5];
    const float* b1    = (const float*)d_in[6];
    const float* w2    = (const float*)d_in[7];
    const float* b2    = (const float*)d_in[8];
    const float* gamma = (const float*)d_in[9];
    const float* beta  = (const float*)d_in[10];
    const float* w_m1  = (const float*)d_in[11];
    const float* b_m1  = (const float*)d_in[12];
    const float* w_m2  = (const float*)d_in[13];
    const float* b_m2  = (const float*)d_in[14];

    const int M = in_sizes[0] / 64;   // n_nodes
    const int E = in_sizes[1] / 2;    // n_edges
    const int* src = eidx;            // edge_index[0]
    const int* tgt = eidx + E;        // edge_index[1] (aggregation target)

    // ws: hagg f32[M*64] | pqh f16[M*128] | ends[M]  = 25.8 MB (cap ~38.6 MB)
    float* hagg     = (float*)d_ws;
    _Float16* pqh   = (_Float16*)(hagg + (size_t)M * 64);
    int*   ends     = (int*)(pqh + (size_t)M * 128);
    // d_out scratch: perm[E] | w2h[2*4096 halfs] | stats[256 floats]
    int* perm = (int*)d_out;
    _Float16* w2h = (_Float16*)((char*)d_out + (size_t)E * 4);
    float* stats  = (float*)((char*)d_out + (size_t)E * 4 + 2 * 4096 * 2);

    dim3 blk(256);
    const int gm64  = (M + 63) / 64;
    const int gelem = (M * 64 + 255) / 256;
    const int gM    = (M + 255) / 256;
    const int gE    = (E + 255) / 256;

    // CSR build + weight pack
    zero_cs<<<gM, blk, 0, stream>>>(ends, stats, M);
    hist_tgt<<<gE, blk, 0, stream>>>(tgt, ends, E);
    scan_counts<<<1, 1024, 0, stream>>>(ends, M);
    fill_csr<<<gE, blk, 0, stream>>>(tgt, ends, perm, E);
    pack_w2<<<4, blk, 0, stream>>>(w2, w2h);

    // h0 = relu(x @ w_in + b_in)
    gemm_k64<64, 64, true, true><<<gm64, blk, 0, stream>>>(x, w_in, b_in, hagg, M);

    for (int l = 0; l < 2; ++l) {
        const float* w1l = w1 + (size_t)l * 144 * 64;
        gemm_pq<<<gm64, blk, 0, stream>>>(hagg, w1l, pqh, M);
        node_agg<<<(M + NPB - 1) / NPB, blk, 0, stream>>>(pqh, ea, src,
            ends, perm,
            w1l + 128 * 64, b1 + l * 64, w2h + (size_t)l * 4096, b2 + l * 64,
            hagg, stats + l * 128, M);
        bn_norm<<<gelem, blk, 0, stream>>>(hagg, stats + l * 128,
            gamma + l * 64, beta + l * 64, M);
    }

    // out = relu(h @ w_m1 + b_m1) @ w_m2 + b_m2
    gemm_k64<64, 64, true, true><<<gm64, blk, 0, stream>>>(hagg, w_m1, b_m1, (float*)pqh, M);
    gemm_k64<32, 64, false, true><<<gm64, blk, 0, stream>>>((float*)pqh, w_m2, b_m2, (float*)d_out, M);
}

// Round 6
// 815.467 us; speedup vs baseline: 1.0943x; 1.0943x over previous
//
#include <hip/hip_runtime.h>
#include <float.h>

// ---------------------------------------------------------------------------
// MPNN forward.  msg@w1 decomposed: per-node p=h@w1a, q=h@w1b (fused gemm_pq,
// f16 output), per-edge ea@w1c fp32 VALU; edge GEMM t1@w2 via f16 MFMA;
// CSR-grouped blocks (7 nodes), LDS segmented max, BN stats fused.
//
// R6: revert to R4-like NPB/ET (R5's occupancy-over-ILP trade regressed);
// 4-deep explicit gather unroll in phase 1 + VGPR cap 128 (not 48) so the
// compiler keeps 4 q-gathers in flight per wave; LDS 38.8 KB -> 4 blocks/CU.
//
// ws budget: hard bound proven R2/R3: ws_size in [38,601,024, 38,617,408).
// Current use: hagg f32 (12.8M) | pq f16 (12.8M) | ends (200K) = 25.8 MB.
// perm/w2h/stats live in d_out (rebuilt each call; head GEMMs overwrite last).
// ---------------------------------------------------------------------------

typedef _Float16 half8 __attribute__((ext_vector_type(8)));
typedef _Float16 half4 __attribute__((ext_vector_type(4)));
typedef float floatx4 __attribute__((ext_vector_type(4)));

__device__ __forceinline__ unsigned enc(float f) {
    unsigned u = __float_as_uint(f);
    return (u & 0x80000000u) ? ~u : (u | 0x80000000u);
}
__device__ __forceinline__ float dec(unsigned u) {
    return (u & 0x80000000u) ? __uint_as_float(u & 0x7fffffffu)
                             : __uint_as_float(~u);
}

// ---------------------------------------------------------------------------
// Generic small GEMM: C[M][N] = op(A[M][64] @ W[64][N] + bias), K fixed = 64.
// ---------------------------------------------------------------------------
template<int N, int M_TILE, bool RELU, bool BIAS>
__global__ __launch_bounds__(256) void gemm_k64(
    const float* __restrict__ A, const float* __restrict__ W,
    const float* __restrict__ bias, float* __restrict__ C, int M)
{
    constexpr int K = 64;
    constexpr int TCOLS = N / 4;
    constexpr int TROWS = 256 / TCOLS;
    constexpr int RPT = M_TILE / TROWS;
    __shared__ __align__(16) float Ws[K * N];
    __shared__ __align__(16) float As[M_TILE * (K + 4)];

    const int t = threadIdx.x;
    const int m0 = blockIdx.x * M_TILE;

    for (int i = t; i < K * N; i += 256) Ws[i] = W[i];

    for (int rr = 0; rr < M_TILE; rr += 16) {
        int r = rr + (t >> 4);
        int c4 = (t & 15) * 4;
        int row = m0 + r;
        float4 v = make_float4(0.f, 0.f, 0.f, 0.f);
        if (row < M) v = *(const float4*)&A[(size_t)row * K + c4];
        *(float4*)&As[r * (K + 4) + c4] = v;
    }
    __syncthreads();

    const int tc = t % TCOLS;
    const int tr = t / TCOLS;
    float4 acc[RPT];
    float4 bv = make_float4(0.f, 0.f, 0.f, 0.f);
    if (BIAS) {
        bv.x = bias[tc * 4 + 0]; bv.y = bias[tc * 4 + 1];
        bv.z = bias[tc * 4 + 2]; bv.w = bias[tc * 4 + 3];
    }
#pragma unroll
    for (int i = 0; i < RPT; ++i) acc[i] = bv;

#pragma unroll 8
    for (int k = 0; k < K; ++k) {
        float4 w = *(const float4*)&Ws[k * N + tc * 4];
#pragma unroll
        for (int i = 0; i < RPT; ++i) {
            float a = As[(tr + i * TROWS) * (K + 4) + k];
            acc[i].x = fmaf(a, w.x, acc[i].x);
            acc[i].y = fmaf(a, w.y, acc[i].y);
            acc[i].z = fmaf(a, w.z, acc[i].z);
            acc[i].w = fmaf(a, w.w, acc[i].w);
        }
    }
#pragma unroll
    for (int i = 0; i < RPT; ++i) {
        int row = m0 + tr + i * TROWS;
        if (row < M) {
            float4 o = acc[i];
            if (RELU) {
                o.x = fmaxf(o.x, 0.f); o.y = fmaxf(o.y, 0.f);
                o.z = fmaxf(o.z, 0.f); o.w = fmaxf(o.w, 0.f);
            }
            *(float4*)&C[(size_t)row * N + tc * 4] = o;
        }
    }
}

// ---------------------------------------------------------------------------
// Fused p|q GEMM, f16 output: PQ[M][128] = (_Float16)(A[M][64] @ [w1a|w1b])
// ---------------------------------------------------------------------------
__global__ __launch_bounds__(256) void gemm_pq(
    const float* __restrict__ A, const float* __restrict__ W,
    _Float16* __restrict__ PQ, int M)
{
    __shared__ __align__(16) float Ws[64 * 128];
    __shared__ __align__(16) float As[64 * 68];

    const int t = threadIdx.x;
    const int m0 = blockIdx.x * 64;

    for (int i = t; i < 64 * 128; i += 256) {
        int k = i >> 7, n = i & 127;
        Ws[i] = W[(size_t)((n < 64 ? k : 64 + k)) * 64 + (n & 63)];
    }
    for (int rr = 0; rr < 64; rr += 16) {
        int r = rr + (t >> 4);
        int c4 = (t & 15) * 4;
        int row = m0 + r;
        float4 v = make_float4(0.f, 0.f, 0.f, 0.f);
        if (row < M) v = *(const float4*)&A[(size_t)row * 64 + c4];
        *(float4*)&As[r * 68 + c4] = v;
    }
    __syncthreads();

    const int tc = t & 31;
    const int tr = t >> 5;
    float4 acc[8];
#pragma unroll
    for (int i = 0; i < 8; ++i) acc[i] = make_float4(0.f, 0.f, 0.f, 0.f);

#pragma unroll 8
    for (int k = 0; k < 64; ++k) {
        float4 w = *(const float4*)&Ws[k * 128 + tc * 4];
#pragma unroll
        for (int i = 0; i < 8; ++i) {
            float a = As[(tr + i * 8) * 68 + k];
            acc[i].x = fmaf(a, w.x, acc[i].x);
            acc[i].y = fmaf(a, w.y, acc[i].y);
            acc[i].z = fmaf(a, w.z, acc[i].z);
            acc[i].w = fmaf(a, w.w, acc[i].w);
        }
    }
#pragma unroll
    for (int i = 0; i < 8; ++i) {
        int row = m0 + tr + i * 8;
        if (row < M) {
            half4 o = { (_Float16)acc[i].x, (_Float16)acc[i].y,
                        (_Float16)acc[i].z, (_Float16)acc[i].w };
            *(half4*)&PQ[(size_t)row * 128 + tc * 4] = o;
        }
    }
}

// ---------------------------------------------------------------------------
// CSR build
// ---------------------------------------------------------------------------
__global__ __launch_bounds__(256) void zero_cs(int* __restrict__ cnt,
                                               float* __restrict__ stats, int M)
{
    int i = blockIdx.x * 256 + threadIdx.x;
    if (i < M) cnt[i] = 0;
    if (blockIdx.x == 0) stats[threadIdx.x] = 0.f;   // 256 floats (2 layers)
}

__global__ __launch_bounds__(256) void hist_tgt(const int* __restrict__ tgt,
                                                int* __restrict__ cnt, int E)
{
    int e = blockIdx.x * 256 + threadIdx.x;
    if (e < E) atomicAdd(&cnt[tgt[e]], 1);
}

__global__ __launch_bounds__(1024) void scan_counts(int* __restrict__ cnt, int M)
{
    __shared__ int part[1024];
    const int t = threadIdx.x;
    const int chunk = (M + 1023) / 1024;
    const int b = t * chunk;
    const int e = min(b + chunk, M);
    int s = 0;
    for (int i = b; i < e; ++i) s += cnt[i];
    part[t] = s;
    __syncthreads();
    for (int off = 1; off < 1024; off <<= 1) {
        int add = (t >= off) ? part[t - off] : 0;
        __syncthreads();
        part[t] += add;
        __syncthreads();
    }
    int run = (t > 0) ? part[t - 1] : 0;
    for (int i = b; i < e; ++i) {
        int v = cnt[i];
        cnt[i] = run;
        run += v;
    }
}

// fill: perm[pos]=e.  After this, arr[n] == end of node n.
__global__ __launch_bounds__(256) void fill_csr(const int* __restrict__ tgt,
    int* __restrict__ arr, int* __restrict__ perm, int E)
{
    int e = blockIdx.x * 256 + threadIdx.x;
    if (e < E) {
        int pos = atomicAdd(&arr[tgt[e]], 1);
        perm[pos] = e;
    }
}

// ---------------------------------------------------------------------------
// Pack w2 (both layers) into f16 MFMA B-fragment order.
// ---------------------------------------------------------------------------
__global__ __launch_bounds__(256) void pack_w2(const float* __restrict__ w2,
                                               _Float16* __restrict__ w2h)
{
    int id = blockIdx.x * 256 + threadIdx.x;
    if (id >= 1024) return;
    int l = id >> 9, rem = id & 511;
    int frag = rem >> 6, lane = rem & 63;
    int nt = frag >> 1, kc = frag & 1;
    const float* W = w2 + (size_t)l * 4096;
    _Float16* O = w2h + (size_t)l * 4096 + (frag * 64 + lane) * 8;
    int n = nt * 16 + (lane & 15);
    int k0 = kc * 32 + (lane >> 4) * 8;
#pragma unroll
    for (int j = 0; j < 8; ++j) O[j] = (_Float16)W[(k0 + j) * 64 + n];
}

// ---------------------------------------------------------------------------
// Fused per-node edge-MLP + segmented max + BN stats.  MFMA phase 2.
//   NPB=7 nodes/block (avg 112 edges, ET=144 -> <0.2% two-tile blocks),
//   LDS ~38.8 KB -> 4 blocks/CU at VGPR<=128.
// ---------------------------------------------------------------------------
#define NPB 7
#define ET  144
#define ETP (ET + 4)   // padding so the 4-deep unroll never reads OOB
#define TSH 72         // t1 LDS row stride in halfs (144 B -> 2-way b128, free)

__global__ __launch_bounds__(256, 4) void node_agg(
    const _Float16* __restrict__ pq, const float* __restrict__ ea,
    const int* __restrict__ srcG,
    const int* __restrict__ ends, const int* __restrict__ perm,
    const float* __restrict__ w1c, const float* __restrict__ b1,
    const _Float16* __restrict__ w2h, const float* __restrict__ b2,
    float* __restrict__ hout, float* __restrict__ stats, int M)
{
    __shared__ __align__(16) _Float16 t1h[ET * TSH];   // 20.7 KB
    __shared__ __align__(16) float eas[ETP * 16];      //  9.5 KB
    __shared__ __align__(16) float w1cs[16 * 64];      //  4.0 KB
    __shared__ __align__(16) float ps[NPB * 64];       //  1.75 KB
    __shared__ __align__(16) unsigned rmu[NPB * 68];   //  1.9 KB
    __shared__ __align__(16) int sidx[ETP];
    __shared__ int endsL[NPB + 1];
    __shared__ unsigned char lnodS[ETP];

    const int t = threadIdx.x;
    const int lane = t & 63;
    const int wid = t >> 6;
    const int n0 = blockIdx.x * NPB;

    for (int i = t; i < 16 * 64; i += 256) w1cs[i] = w1c[i];
    if (t <= NPB) {
        int n = n0 + t - 1;
        endsL[t] = (t == 0) ? ((n0 == 0) ? 0 : ends[n0 - 1])
                            : ((n < M) ? ends[n] : ends[M - 1]);
    }
    {
        int c = t & 63;
        for (int nn = t >> 6; nn < NPB; nn += 4) {
            int node = n0 + nn;
            ps[nn * 64 + c] =
                ((node < M) ? (float)pq[(size_t)node * 128 + c] : 0.f) + b1[c];
        }
    }
    for (int i = t; i < NPB * 68; i += 256) rmu[i] = 0u;   // 0 < enc(anything)

    // B fragments (w2), same for all waves
    half8 bfrag[4][2];
#pragma unroll
    for (int nt = 0; nt < 4; ++nt)
#pragma unroll
        for (int kc = 0; kc < 2; ++kc)
            bfrag[nt][kc] = *(const half8*)(w2h + ((nt * 2 + kc) * 64 + lane) * 8);

    __syncthreads();

    const int eBeg = endsL[0], eEnd = endsL[NPB];

    for (int tile = eBeg; tile < eEnd; tile += ET) {
        const int cnt = min(ET, eEnd - tile);

        // ---- stage metadata + edge_attr (one barrier) ----
        for (int i = t; i < ETP; i += 256) {
            if (i < cnt) {
                int gp = tile + i;
                sidx[i] = srcG[perm[gp]];
                int L = 0;
                while (gp >= endsL[L + 1]) ++L;
                lnodS[i] = (unsigned char)L;
            } else { sidx[i] = 0; lnodS[i] = 0; }
        }
        for (int i = t; i < ETP * 16; i += 256) {
            int ei = i >> 4;
            float v = 0.f;
            if (ei < cnt) {
                int pe = perm[tile + ei];          // uniform per 16 lanes (L2 broadcast)
                v = ea[(size_t)pe * 16 + (i & 15)];
            }
            eas[i] = v;
        }
        __syncthreads();

        // ---- phase 1: t1 = relu(p[tgt]+b1 + q[src] + ea@w1c) -> f16 LDS ----
        // 4-deep unroll: 4 independent q-gathers in flight per wave.
        {
            const int c = t & 63;
            for (int i0 = wid * 4; i0 < cnt; i0 += 16) {
                float acc[4];
#pragma unroll
                for (int e = 0; e < 4; ++e) {
                    int ie = i0 + e;                     // < ETP (padded)
                    int s = sidx[ie];
                    float qv = (float)pq[(size_t)s * 128 + 64 + c];
                    acc[e] = ps[lnodS[ie] * 64 + c] + qv;
                }
#pragma unroll
                for (int j = 0; j < 16; ++j) {
                    const float w = w1cs[j * 64 + c];
#pragma unroll
                    for (int e = 0; e < 4; ++e)
                        acc[e] = fmaf(eas[(i0 + e) * 16 + j], w, acc[e]);
                }
#pragma unroll
                for (int e = 0; e < 4; ++e) {
                    int ie = i0 + e;
                    if (ie < cnt)
                        t1h[ie * TSH + c] = (_Float16)fmaxf(acc[e], 0.f);
                }
            }
        }
        __syncthreads();

        // ---- phase 2: m = t1 @ w2 via MFMA, segmented max into rmu ----
        {
            const int quad = lane >> 4;
            const int col = lane & 15;
            for (int mt = wid; mt * 16 < cnt; mt += 4) {
                const int e0 = mt * 16;
                floatx4 acc[4] = {{0.f,0.f,0.f,0.f},{0.f,0.f,0.f,0.f},
                                  {0.f,0.f,0.f,0.f},{0.f,0.f,0.f,0.f}};
#pragma unroll
                for (int kc = 0; kc < 2; ++kc) {
                    half8 a = *(const half8*)&t1h[(e0 + col) * TSH + kc * 32 + quad * 8];
#pragma unroll
                    for (int nt = 0; nt < 4; ++nt)
                        acc[nt] = __builtin_amdgcn_mfma_f32_16x16x32_f16(
                            a, bfrag[nt][kc], acc[nt], 0, 0, 0);
                }
                const int r0 = e0 + quad * 4;
#pragma unroll
                for (int nt = 0; nt < 4; ++nt) {
                    int curL = -1;
                    float best = 0.f;
#pragma unroll
                    for (int r = 0; r < 4; ++r) {
                        int ge = r0 + r;
                        if (ge < cnt) {
                            int L = lnodS[ge];
                            float v = acc[nt][r];
                            if (L != curL) {
                                if (curL >= 0)
                                    atomicMax(&rmu[curL * 68 + nt * 16 + col], enc(best));
                                curL = L; best = v;
                            } else best = fmaxf(best, v);
                        }
                    }
                    if (curL >= 0)
                        atomicMax(&rmu[curL * 68 + nt * 16 + col], enc(best));
                }
            }
        }
        __syncthreads();
    }

    // ---- final store (+b2) + BN stats ----
    for (int idx = t; idx < NPB * 64; idx += 256) {
        int L = idx >> 6, c = idx & 63;
        int node = n0 + L;
        float v = 0.f;
        if (node < M) {
            if (endsL[L + 1] > endsL[L]) v = dec(rmu[L * 68 + c]) + b2[c];
            hout[(size_t)node * 64 + c] = v;
        }
        ((float*)rmu)[L * 68 + c] = v;   // own slot: no race
    }
    __syncthreads();
    if (t < 64) {
        float s = 0.f, s2 = 0.f;
#pragma unroll
        for (int L = 0; L < NPB; ++L) {
            float v = ((float*)rmu)[L * 68 + t];
            s += v;
            s2 = fmaf(v, v, s2);
        }
        atomicAdd(&stats[t], s);
        atomicAdd(&stats[64 + t], s2);
    }
}

// ---------------------------------------------------------------------------
// BN normalize + relu, in place
// ---------------------------------------------------------------------------
__global__ __launch_bounds__(256) void bn_norm(float* __restrict__ h,
    const float* __restrict__ stats, const float* __restrict__ gamma,
    const float* __restrict__ beta, int M)
{
    int idx = blockIdx.x * 256 + threadIdx.x;
    if (idx >= M * 64) return;
    int c = idx & 63;
    float inv = 1.f / (float)M;
    float mu = stats[c] * inv;
    float var = fmaxf(stats[64 + c] * inv - mu * mu, 0.f);
    float v = h[idx];
    h[idx] = fmaxf(gamma[c] * (v - mu) * rsqrtf(var + 1e-5f) + beta[c], 0.f);
}

// ---------------------------------------------------------------------------
extern "C" void kernel_launch(void* const* d_in, const int* in_sizes, int n_in,
                              void* d_out, int out_size, void* d_ws, size_t ws_size,
                              hipStream_t stream)
{
    const float* x     = (const float*)d_in[0];
    const int*   eidx  = (const int*)  d_in[1];
    const float* ea    = (const float*)d_in[2];
    const float* w_in  = (const float*)d_in[3];
    const float* b_in  = (const float*)d_in[4];
    const float* w1    = (const float*)d_in[5];
    const float* b1    = (const float*)d_in[6];
    const float* w2    = (const float*)d_in[7];
    const float* b2    = (const float*)d_in[8];
    const float* gamma = (const float*)d_in[9];
    const float* beta  = (const float*)d_in[10];
    const float* w_m1  = (const float*)d_in[11];
    const float* b_m1  = (const float*)d_in[12];
    const float* w_m2  = (const float*)d_in[13];
    const float* b_m2  = (const float*)d_in[14];

    const int M = in_sizes[0] / 64;   // n_nodes
    const int E = in_sizes[1] / 2;    // n_edges
    const int* src = eidx;            // edge_index[0]
    const int* tgt = eidx + E;        // edge_index[1] (aggregation target)

    // ws: hagg f32[M*64] | pqh f16[M*128] | ends[M]  = 25.8 MB (cap ~38.6 MB)
    float* hagg     = (float*)d_ws;
    _Float16* pqh   = (_Float16*)(hagg + (size_t)M * 64);
    int*   ends     = (int*)(pqh + (size_t)M * 128);
    // d_out scratch: perm[E] | w2h[2*4096 halfs] | stats[256 floats]
    int* perm = (int*)d_out;
    _Float16* w2h = (_Float16*)((char*)d_out + (size_t)E * 4);
    float* stats  = (float*)((char*)d_out + (size_t)E * 4 + 2 * 4096 * 2);

    dim3 blk(256);
    const int gm64  = (M + 63) / 64;
    const int gelem = (M * 64 + 255) / 256;
    const int gM    = (M + 255) / 256;
    const int gE    = (E + 255) / 256;

    // CSR build + weight pack
    zero_cs<<<gM, blk, 0, stream>>>(ends, stats, M);
    hist_tgt<<<gE, blk, 0, stream>>>(tgt, ends, E);
    scan_counts<<<1, 1024, 0, stream>>>(ends, M);
    fill_csr<<<gE, blk, 0, stream>>>(tgt, ends, perm, E);
    pack_w2<<<4, blk, 0, stream>>>(w2, w2h);

    // h0 = relu(x @ w_in + b_in)
    gemm_k64<64, 64, true, true><<<gm64, blk, 0, stream>>>(x, w_in, b_in, hagg, M);

    for (int l = 0; l < 2; ++l) {
        const float* w1l = w1 + (size_t)l * 144 * 64;
        gemm_pq<<<gm64, blk, 0, stream>>>(hagg, w1l, pqh, M);
        node_agg<<<(M + NPB - 1) / NPB, blk, 0, stream>>>(pqh, ea, src,
            ends, perm,
            w1l + 128 * 64, b1 + l * 64, w2h + (size_t)l * 4096, b2 + l * 64,
            hagg, stats + l * 128, M);
        bn_norm<<<gelem, blk, 0, stream>>>(hagg, stats + l * 128,
            gamma + l * 64, beta + l * 64, M);
    }

    // out = relu(h @ w_m1 + b_m1) @ w_m2 + b_m2
    gemm_k64<64, 64, true, true><<<gm64, blk, 0, stream>>>(hagg, w_m1, b_m1, (float*)pqh, M);
    gemm_k64<32, 64, false, true><<<gm64, blk, 0, stream>>>((float*)pqh, w_m2, b_m2, (float*)d_out, M);
}

// Round 7
// 789.407 us; speedup vs baseline: 1.1304x; 1.0330x over previous
//
#include <hip/hip_runtime.h>
#include <float.h>

// ---------------------------------------------------------------------------
// MPNN forward.  msg@w1 decomposed: per-node p=h@w1a, q=h@w1b (fused gemm_pq,
// f16 output), per-edge ea@w1c fp32 VALU (w1c in per-lane VGPRs, eas read as
// float4 broadcasts); edge GEMM t1@w2 via f16 MFMA; CSR-grouped blocks
// (6 nodes), LDS segmented max, BN stats fused.  Multi-block CSR scan.
//
// ws budget: hard bound proven R2/R3: ws_size in [38,601,024, 38,617,408).
// Use: hagg f32 (12.8M) | pq f16 (12.8M) | ends (200K) | partials (784B).
// perm/w2h/stats live in d_out (rebuilt each call; head GEMMs overwrite last).
// ---------------------------------------------------------------------------

typedef _Float16 half8 __attribute__((ext_vector_type(8)));
typedef _Float16 half4 __attribute__((ext_vector_type(4)));
typedef float floatx4 __attribute__((ext_vector_type(4)));

__device__ __forceinline__ unsigned enc(float f) {
    unsigned u = __float_as_uint(f);
    return (u & 0x80000000u) ? ~u : (u | 0x80000000u);
}
__device__ __forceinline__ float dec(unsigned u) {
    return (u & 0x80000000u) ? __uint_as_float(u & 0x7fffffffu)
                             : __uint_as_float(~u);
}

// ---------------------------------------------------------------------------
// Generic small GEMM: C[M][N] = op(A[M][64] @ W[64][N] + bias), K fixed = 64.
// ---------------------------------------------------------------------------
template<int N, int M_TILE, bool RELU, bool BIAS>
__global__ __launch_bounds__(256) void gemm_k64(
    const float* __restrict__ A, const float* __restrict__ W,
    const float* __restrict__ bias, float* __restrict__ C, int M)
{
    constexpr int K = 64;
    constexpr int TCOLS = N / 4;
    constexpr int TROWS = 256 / TCOLS;
    constexpr int RPT = M_TILE / TROWS;
    __shared__ __align__(16) float Ws[K * N];
    __shared__ __align__(16) float As[M_TILE * (K + 4)];

    const int t = threadIdx.x;
    const int m0 = blockIdx.x * M_TILE;

    for (int i = t; i < K * N; i += 256) Ws[i] = W[i];

    for (int rr = 0; rr < M_TILE; rr += 16) {
        int r = rr + (t >> 4);
        int c4 = (t & 15) * 4;
        int row = m0 + r;
        float4 v = make_float4(0.f, 0.f, 0.f, 0.f);
        if (row < M) v = *(const float4*)&A[(size_t)row * K + c4];
        *(float4*)&As[r * (K + 4) + c4] = v;
    }
    __syncthreads();

    const int tc = t % TCOLS;
    const int tr = t / TCOLS;
    float4 acc[RPT];
    float4 bv = make_float4(0.f, 0.f, 0.f, 0.f);
    if (BIAS) {
        bv.x = bias[tc * 4 + 0]; bv.y = bias[tc * 4 + 1];
        bv.z = bias[tc * 4 + 2]; bv.w = bias[tc * 4 + 3];
    }
#pragma unroll
    for (int i = 0; i < RPT; ++i) acc[i] = bv;

#pragma unroll 8
    for (int k = 0; k < K; ++k) {
        float4 w = *(const float4*)&Ws[k * N + tc * 4];
#pragma unroll
        for (int i = 0; i < RPT; ++i) {
            float a = As[(tr + i * TROWS) * (K + 4) + k];
            acc[i].x = fmaf(a, w.x, acc[i].x);
            acc[i].y = fmaf(a, w.y, acc[i].y);
            acc[i].z = fmaf(a, w.z, acc[i].z);
            acc[i].w = fmaf(a, w.w, acc[i].w);
        }
    }
#pragma unroll
    for (int i = 0; i < RPT; ++i) {
        int row = m0 + tr + i * TROWS;
        if (row < M) {
            float4 o = acc[i];
            if (RELU) {
                o.x = fmaxf(o.x, 0.f); o.y = fmaxf(o.y, 0.f);
                o.z = fmaxf(o.z, 0.f); o.w = fmaxf(o.w, 0.f);
            }
            *(float4*)&C[(size_t)row * N + tc * 4] = o;
        }
    }
}

// ---------------------------------------------------------------------------
// Fused p|q GEMM, f16 output: PQ[M][128] = (_Float16)(A[M][64] @ [w1a|w1b])
// ---------------------------------------------------------------------------
__global__ __launch_bounds__(256) void gemm_pq(
    const float* __restrict__ A, const float* __restrict__ W,
    _Float16* __restrict__ PQ, int M)
{
    __shared__ __align__(16) float Ws[64 * 128];
    __shared__ __align__(16) float As[64 * 68];

    const int t = threadIdx.x;
    const int m0 = blockIdx.x * 64;

    for (int i = t; i < 64 * 128; i += 256) {
        int k = i >> 7, n = i & 127;
        Ws[i] = W[(size_t)((n < 64 ? k : 64 + k)) * 64 + (n & 63)];
    }
    for (int rr = 0; rr < 64; rr += 16) {
        int r = rr + (t >> 4);
        int c4 = (t & 15) * 4;
        int row = m0 + r;
        float4 v = make_float4(0.f, 0.f, 0.f, 0.f);
        if (row < M) v = *(const float4*)&A[(size_t)row * 64 + c4];
        *(float4*)&As[r * 68 + c4] = v;
    }
    __syncthreads();

    const int tc = t & 31;
    const int tr = t >> 5;
    float4 acc[8];
#pragma unroll
    for (int i = 0; i < 8; ++i) acc[i] = make_float4(0.f, 0.f, 0.f, 0.f);

#pragma unroll 8
    for (int k = 0; k < 64; ++k) {
        float4 w = *(const float4*)&Ws[k * 128 + tc * 4];
#pragma unroll
        for (int i = 0; i < 8; ++i) {
            float a = As[(tr + i * 8) * 68 + k];
            acc[i].x = fmaf(a, w.x, acc[i].x);
            acc[i].y = fmaf(a, w.y, acc[i].y);
            acc[i].z = fmaf(a, w.z, acc[i].z);
            acc[i].w = fmaf(a, w.w, acc[i].w);
        }
    }
#pragma unroll
    for (int i = 0; i < 8; ++i) {
        int row = m0 + tr + i * 8;
        if (row < M) {
            half4 o = { (_Float16)acc[i].x, (_Float16)acc[i].y,
                        (_Float16)acc[i].z, (_Float16)acc[i].w };
            *(half4*)&PQ[(size_t)row * 128 + tc * 4] = o;
        }
    }
}

// ---------------------------------------------------------------------------
// CSR build: hist -> multi-block exclusive scan -> fill(perm)
// ---------------------------------------------------------------------------
__global__ __launch_bounds__(256) void hist_tgt(const int* __restrict__ tgt,
                                                int* __restrict__ cnt, int E)
{
    int e = blockIdx.x * 256 + threadIdx.x;
    if (e < E) atomicAdd(&cnt[tgt[e]], 1);
}

// partial[b] = sum of cnt[b*256 .. b*256+255]
__global__ __launch_bounds__(256) void scan_partial(const int* __restrict__ cnt,
                                                    int* __restrict__ part, int M)
{
    __shared__ int s[256];
    int i = blockIdx.x * 256 + threadIdx.x;
    s[threadIdx.x] = (i < M) ? cnt[i] : 0;
    __syncthreads();
    for (int off = 128; off > 0; off >>= 1) {
        if (threadIdx.x < off) s[threadIdx.x] += s[threadIdx.x + off];
        __syncthreads();
    }
    if (threadIdx.x == 0) part[blockIdx.x] = s[0];
}

// exclusive scan of part[0..nb) in one block (nb <= 256)
__global__ __launch_bounds__(256) void scan_part2(int* __restrict__ part, int nb)
{
    __shared__ int s[256];
    int t = threadIdx.x;
    int v = (t < nb) ? part[t] : 0;
    s[t] = v;
    __syncthreads();
    for (int off = 1; off < 256; off <<= 1) {
        int a = (t >= off) ? s[t - off] : 0;
        __syncthreads();
        s[t] += a;
        __syncthreads();
    }
    if (t < nb) part[t] = s[t] - v;   // exclusive
}

// cnt[i] = exclusive_scan(cnt)[i] (within-block scan + block offset)
__global__ __launch_bounds__(256) void scan_add(int* __restrict__ cnt,
                                                const int* __restrict__ part, int M)
{
    __shared__ int s[256];
    int t = threadIdx.x;
    int i = blockIdx.x * 256 + t;
    int v = (i < M) ? cnt[i] : 0;
    s[t] = v;
    __syncthreads();
    for (int off = 1; off < 256; off <<= 1) {
        int a = (t >= off) ? s[t - off] : 0;
        __syncthreads();
        s[t] += a;
        __syncthreads();
    }
    if (i < M) cnt[i] = part[blockIdx.x] + s[t] - v;
}

// fill: perm[pos]=e.  After this, arr[n] == end of node n.
__global__ __launch_bounds__(256) void fill_csr(const int* __restrict__ tgt,
    int* __restrict__ arr, int* __restrict__ perm, int E)
{
    int e = blockIdx.x * 256 + threadIdx.x;
    if (e < E) {
        int pos = atomicAdd(&arr[tgt[e]], 1);
        perm[pos] = e;
    }
}

// ---------------------------------------------------------------------------
// Pack w2 (both layers) into f16 MFMA B-fragment order.
// ---------------------------------------------------------------------------
__global__ __launch_bounds__(256) void pack_w2(const float* __restrict__ w2,
                                               _Float16* __restrict__ w2h)
{
    int id = blockIdx.x * 256 + threadIdx.x;
    if (id >= 1024) return;
    int l = id >> 9, rem = id & 511;
    int frag = rem >> 6, lane = rem & 63;
    int nt = frag >> 1, kc = frag & 1;
    const float* W = w2 + (size_t)l * 4096;
    _Float16* O = w2h + (size_t)l * 4096 + (frag * 64 + lane) * 8;
    int n = nt * 16 + (lane & 15);
    int k0 = kc * 32 + (lane >> 4) * 8;
#pragma unroll
    for (int j = 0; j < 8; ++j) O[j] = (_Float16)W[(k0 + j) * 64 + n];
}

// ---------------------------------------------------------------------------
// Fused per-node edge-MLP + segmented max + BN stats.  MFMA phase 2.
//   NPB=6 nodes/block (mean 96 edges, ET=128 -> ~0.05% two-tile blocks),
//   LDS ~30.7 KB; w1c lives in 16 per-lane VGPRs; eas read as b128 broadcast.
// ---------------------------------------------------------------------------
#define NPB 6
#define ET  128
#define ETP (ET + 4)   // padding so the 4-deep unroll never reads OOB
#define TSH 72         // t1 LDS row stride in halfs (144 B -> 2-way b128, free)

__global__ __launch_bounds__(256, 4) void node_agg(
    const _Float16* __restrict__ pq, const float* __restrict__ ea,
    const int* __restrict__ srcG,
    const int* __restrict__ ends, const int* __restrict__ perm,
    const float* __restrict__ w1c, const float* __restrict__ b1,
    const _Float16* __restrict__ w2h, const float* __restrict__ b2,
    float* __restrict__ hout, float* __restrict__ stats, int M)
{
    __shared__ __align__(16) _Float16 t1h[ET * TSH];   // 18.4 KB
    __shared__ __align__(16) float eas[ETP * 16];      //  8.4 KB
    __shared__ __align__(16) float ps[NPB * 64];       //  1.5 KB
    __shared__ __align__(16) unsigned rmu[NPB * 68];   //  1.6 KB
    __shared__ __align__(16) int sidx[ETP];
    __shared__ int endsL[NPB + 1];
    __shared__ unsigned char lnodS[ETP];

    const int t = threadIdx.x;
    const int lane = t & 63;
    const int wid = t >> 6;
    const int n0 = blockIdx.x * NPB;
    const int c = lane;

    // w1c column c -> 16 VGPRs (coalesced loads, once per block)
    float w1r[16];
#pragma unroll
    for (int j = 0; j < 16; ++j) w1r[j] = w1c[j * 64 + c];

    if (t <= NPB) {
        int n = n0 + t - 1;
        endsL[t] = (t == 0) ? ((n0 == 0) ? 0 : ends[n0 - 1])
                            : ((n < M) ? ends[n] : ends[M - 1]);
    }
    for (int nn = wid; nn < NPB; nn += 4) {
        int node = n0 + nn;
        ps[nn * 64 + c] =
            ((node < M) ? (float)pq[(size_t)node * 128 + c] : 0.f) + b1[c];
    }
    for (int i = t; i < NPB * 68; i += 256) rmu[i] = 0u;   // 0 < enc(anything)

    // B fragments (w2), same for all waves
    half8 bfrag[4][2];
#pragma unroll
    for (int nt = 0; nt < 4; ++nt)
#pragma unroll
        for (int kc = 0; kc < 2; ++kc)
            bfrag[nt][kc] = *(const half8*)(w2h + ((nt * 2 + kc) * 64 + lane) * 8);

    __syncthreads();

    const int eBeg = endsL[0], eEnd = endsL[NPB];

    for (int tile = eBeg; tile < eEnd; tile += ET) {
        const int cnt = min(ET, eEnd - tile);

        // ---- stage metadata + edge_attr (one barrier) ----
        for (int i = t; i < ETP; i += 256) {
            if (i < cnt) {
                int gp = tile + i;
                sidx[i] = srcG[perm[gp]];
                int L = 0;
                while (gp >= endsL[L + 1]) ++L;
                lnodS[i] = (unsigned char)L;
            } else { sidx[i] = 0; lnodS[i] = 0; }
        }
        for (int i4 = t; i4 < ETP * 4; i4 += 256) {       // float4 granularity
            int ei = i4 >> 2, j4 = i4 & 3;
            float4 v = make_float4(0.f, 0.f, 0.f, 0.f);
            if (ei < cnt) {
                int pe = perm[tile + ei];                  // 4 lanes share (L2 bcast)
                v = *(const float4*)&ea[(size_t)pe * 16 + j4 * 4];
            }
            *(float4*)&eas[ei * 16 + j4 * 4] = v;
        }
        __syncthreads();

        // ---- phase 1: t1 = relu(p[tgt]+b1 + q[src] + ea@w1c) -> f16 LDS ----
        // 4-deep unroll; eas via b128 broadcasts; w1c in VGPRs.
        for (int i0 = wid * 4; i0 < cnt; i0 += 16) {
            float acc[4];
#pragma unroll
            for (int e = 0; e < 4; ++e) {
                int ie = i0 + e;                           // < ETP (padded)
                acc[e] = ps[lnodS[ie] * 64 + c]
                       + (float)pq[(size_t)sidx[ie] * 128 + 64 + c];
            }
#pragma unroll
            for (int j4 = 0; j4 < 4; ++j4) {
#pragma unroll
                for (int e = 0; e < 4; ++e) {
                    float4 ev = *(const float4*)&eas[(i0 + e) * 16 + j4 * 4];
                    acc[e] = fmaf(ev.x, w1r[j4 * 4 + 0], acc[e]);
                    acc[e] = fmaf(ev.y, w1r[j4 * 4 + 1], acc[e]);
                    acc[e] = fmaf(ev.z, w1r[j4 * 4 + 2], acc[e]);
                    acc[e] = fmaf(ev.w, w1r[j4 * 4 + 3], acc[e]);
                }
            }
#pragma unroll
            for (int e = 0; e < 4; ++e) {
                int ie = i0 + e;
                if (ie < cnt)
                    t1h[ie * TSH + c] = (_Float16)fmaxf(acc[e], 0.f);
            }
        }
        __syncthreads();

        // ---- phase 2: m = t1 @ w2 via MFMA, segmented max into rmu ----
        {
            const int quad = lane >> 4;
            const int col = lane & 15;
            for (int mt = wid; mt * 16 < cnt; mt += 4) {
                const int e0 = mt * 16;
                floatx4 acc[4] = {{0.f,0.f,0.f,0.f},{0.f,0.f,0.f,0.f},
                                  {0.f,0.f,0.f,0.f},{0.f,0.f,0.f,0.f}};
#pragma unroll
                for (int kc = 0; kc < 2; ++kc) {
                    half8 a = *(const half8*)&t1h[(e0 + col) * TSH + kc * 32 + quad * 8];
#pragma unroll
                    for (int nt = 0; nt < 4; ++nt)
                        acc[nt] = __builtin_amdgcn_mfma_f32_16x16x32_f16(
                            a, bfrag[nt][kc], acc[nt], 0, 0, 0);
                }
                const int r0 = e0 + quad * 4;
#pragma unroll
                for (int nt = 0; nt < 4; ++nt) {
                    int curL = -1;
                    float best = 0.f;
#pragma unroll
                    for (int r = 0; r < 4; ++r) {
                        int ge = r0 + r;
                        if (ge < cnt) {
                            int L = lnodS[ge];
                            float v = acc[nt][r];
                            if (L != curL) {
                                if (curL >= 0)
                                    atomicMax(&rmu[curL * 68 + nt * 16 + col], enc(best));
                                curL = L; best = v;
                            } else best = fmaxf(best, v);
                        }
                    }
                    if (curL >= 0)
                        atomicMax(&rmu[curL * 68 + nt * 16 + col], enc(best));
                }
            }
        }
        __syncthreads();
    }

    // ---- final store (+b2) + BN stats ----
    for (int idx = t; idx < NPB * 64; idx += 256) {
        int L = idx >> 6, cc = idx & 63;
        int node = n0 + L;
        float v = 0.f;
        if (node < M) {
            if (endsL[L + 1] > endsL[L]) v = dec(rmu[L * 68 + cc]) + b2[cc];
            hout[(size_t)node * 64 + cc] = v;
        }
        ((float*)rmu)[L * 68 + cc] = v;   // own slot: no race
    }
    __syncthreads();
    if (t < 64) {
        float s = 0.f, s2 = 0.f;
#pragma unroll
        for (int L = 0; L < NPB; ++L) {
            float v = ((float*)rmu)[L * 68 + t];
            s += v;
            s2 = fmaf(v, v, s2);
        }
        atomicAdd(&stats[t], s);
        atomicAdd(&stats[64 + t], s2);
    }
}

// ---------------------------------------------------------------------------
// BN normalize + relu, in place
// ---------------------------------------------------------------------------
__global__ __launch_bounds__(256) void bn_norm(float* __restrict__ h,
    const float* __restrict__ stats, const float* __restrict__ gamma,
    const float* __restrict__ beta, int M)
{
    int idx = blockIdx.x * 256 + threadIdx.x;
    if (idx >= M * 64) return;
    int c = idx & 63;
    float inv = 1.f / (float)M;
    float mu = stats[c] * inv;
    float var = fmaxf(stats[64 + c] * inv - mu * mu, 0.f);
    float v = h[idx];
    h[idx] = fmaxf(gamma[c] * (v - mu) * rsqrtf(var + 1e-5f) + beta[c], 0.f);
}

// ---------------------------------------------------------------------------
extern "C" void kernel_launch(void* const* d_in, const int* in_sizes, int n_in,
                              void* d_out, int out_size, void* d_ws, size_t ws_size,
                              hipStream_t stream)
{
    const float* x     = (const float*)d_in[0];
    const int*   eidx  = (const int*)  d_in[1];
    const float* ea    = (const float*)d_in[2];
    const float* w_in  = (const float*)d_in[3];
    const float* b_in  = (const float*)d_in[4];
    const float* w1    = (const float*)d_in[5];
    const float* b1    = (const float*)d_in[6];
    const float* w2    = (const float*)d_in[7];
    const float* b2    = (const float*)d_in[8];
    const float* gamma = (const float*)d_in[9];
    const float* beta  = (const float*)d_in[10];
    const float* w_m1  = (const float*)d_in[11];
    const float* b_m1  = (const float*)d_in[12];
    const float* w_m2  = (const float*)d_in[13];
    const float* b_m2  = (const float*)d_in[14];

    const int M = in_sizes[0] / 64;   // n_nodes
    const int E = in_sizes[1] / 2;    // n_edges
    const int* src = eidx;            // edge_index[0]
    const int* tgt = eidx + E;        // edge_index[1] (aggregation target)

    // ws: hagg f32[M*64] | pqh f16[M*128] | ends[M] | part[nb]  = 25.8 MB
    float* hagg     = (float*)d_ws;
    _Float16* pqh   = (_Float16*)(hagg + (size_t)M * 64);
    int*   ends     = (int*)(pqh + (size_t)M * 128);
    const int nb    = (M + 255) / 256;           // 196 scan partials
    int*   part     = ends + M;
    // d_out scratch: perm[E] | w2h[2*4096 halfs] | stats[256 floats]
    int* perm = (int*)d_out;
    _Float16* w2h = (_Float16*)((char*)d_out + (size_t)E * 4);
    float* stats  = (float*)((char*)d_out + (size_t)E * 4 + 2 * 4096 * 2);

    dim3 blk(256);
    const int gm64  = (M + 63) / 64;
    const int gelem = (M * 64 + 255) / 256;
    const int gE    = (E + 255) / 256;

    // CSR build + weight pack
    hipMemsetAsync(ends, 0, (size_t)M * 4, stream);
    hipMemsetAsync(stats, 0, 256 * 4, stream);
    hist_tgt<<<gE, blk, 0, stream>>>(tgt, ends, E);
    scan_partial<<<nb, blk, 0, stream>>>(ends, part, M);
    scan_part2<<<1, blk, 0, stream>>>(part, nb);
    scan_add<<<nb, blk, 0, stream>>>(ends, part, M);
    fill_csr<<<gE, blk, 0, stream>>>(tgt, ends, perm, E);
    pack_w2<<<4, blk, 0, stream>>>(w2, w2h);

    // h0 = relu(x @ w_in + b_in)
    gemm_k64<64, 64, true, true><<<gm64, blk, 0, stream>>>(x, w_in, b_in, hagg, M);

    for (int l = 0; l < 2; ++l) {
        const float* w1l = w1 + (size_t)l * 144 * 64;
        gemm_pq<<<gm64, blk, 0, stream>>>(hagg, w1l, pqh, M);
        node_agg<<<(M + NPB - 1) / NPB, blk, 0, stream>>>(pqh, ea, src,
            ends, perm,
            w1l + 128 * 64, b1 + l * 64, w2h + (size_t)l * 4096, b2 + l * 64,
            hagg, stats + l * 128, M);
        bn_norm<<<gelem, blk, 0, stream>>>(hagg, stats + l * 128,
            gamma + l * 64, beta + l * 64, M);
    }

    // out = relu(h @ w_m1 + b_m1) @ w_m2 + b_m2
    gemm_k64<64, 64, true, true><<<gm64, blk, 0, stream>>>(hagg, w_m1, b_m1, (float*)pqh, M);
    gemm_k64<32, 64, false, true><<<gm64, blk, 0, stream>>>((float*)pqh, w_m2, b_m2, (float*)d_out, M);
}